// Round 9
// baseline (2203.295 us; speedup 1.0000x reference)
//
#include <hip/hip_runtime.h>

// Swin window attention, round 9: split pipeline; GEMM gets the T3 2-phase
// software pipeline. r8 profile: qkv gemm 188us at MfmaUtil 9% / HBM 10% /
// occ 21% -- stage->barrier->compute->barrier exposed L2 latency per slice.
// Fix: BN=32 double-buffered panels (49 KB LDS, 3 blocks/CU), reg-staged
// issue-early/write-late: {load t+1 -> regs; compute t; ds_write t+1; barrier}.
// One barrier/slice; panel granule-swizzle baked into the weight image at prep.
// Attn kernel unchanged from r7/r8 (isolate the delta).

#define NTOK 49
#define DIM 384
#define HEADS 12
#define QKV_OC 1152
#define QKV_ELEMS (1152*384)
#define PROJ_ELEMS (384*384)
#define CMB_ELEMS (64*12*49*49)
#define SCALE 0.17677669529663687f

typedef __attribute__((ext_vector_type(8))) __bf16 bf16x8;
typedef __attribute__((ext_vector_type(4))) float f32x4;

union BF8 { bf16x8 v; unsigned short u[8]; uint4 q; };

__device__ __forceinline__ unsigned short f2bf(float f) {
  union { float f; unsigned u; } x; x.f = f;
  unsigned r = x.u + 0x7fffu + ((x.u >> 16) & 1u);   // RNE
  return (unsigned short)(r >> 16);
}

__device__ __forceinline__ bf16x8 zbf8() {
  BF8 z;
  #pragma unroll
  for (int j = 0; j < 8; ++j) z.u[j] = 0;
  return z.v;
}

// ---- prep: weights -> bf16 swizzled image (scale folded), cmb, scaled bias --
// image[c][s*8+e] = W[c][(s^(c&7))*8 + e]  (granule swizzle baked in)
__global__ void prep_kernel(const float* __restrict__ qkv_w,
                            const float* __restrict__ proj_w,
                            const float* __restrict__ bias_table,
                            const int* __restrict__ rel_idx,
                            const float* __restrict__ mask,
                            const float* __restrict__ qkv_b,
                            unsigned short* __restrict__ wq,
                            unsigned short* __restrict__ wp,
                            float* __restrict__ cmb,
                            float* __restrict__ qb2) {
  int i = blockIdx.x * 256 + threadIdx.x;
  if (i < QKV_ELEMS) {
    int c = i / 384, j = i % 384, s = j >> 3, e = j & 7;
    float v = qkv_w[c * 384 + ((s ^ (c & 7)) << 3) + e];
    if (c < 384) v *= SCALE;                  // q out-cols get the softmax scale
    wq[i] = f2bf(v);
  } else if (i < QKV_ELEMS + PROJ_ELEMS) {
    int k = i - QKV_ELEMS;
    int c = k / 384, j = k % 384, s = j >> 3, e = j & 7;
    wp[k] = f2bf(proj_w[c * 384 + ((s ^ (c & 7)) << 3) + e]);
  } else if (i < QKV_ELEMS + PROJ_ELEMS + CMB_ELEMS) {
    int j = i - QKV_ELEMS - PROJ_ELEMS;
    // layout: ((wi*12 + h)*49 + tok)*49 + qrow
    int row = j % 49;
    int tok = (j / 49) % 49;
    int h   = (j / 2401) % 12;
    int wi  = j / (2401 * 12);
    cmb[j] = bias_table[rel_idx[row * 49 + tok] * HEADS + h]
           + mask[(wi * 49 + row) * 49 + tok];
  } else if (i < QKV_ELEMS + PROJ_ELEMS + CMB_ELEMS + QKV_OC) {
    int c = i - QKV_ELEMS - PROJ_ELEMS - CMB_ELEMS;
    qb2[c] = qkv_b[c] * (c < 384 ? SCALE : 1.0f);
  }
}

// ---- gemm_pipe: C[M][NS*32] = A[M][384] @ W[NS*32][384]^T + bias ----------
// Block = 64 rows (4 waves x 16), A-frags resident. NS slices of 32 out-cols;
// double-buffered [32][384] panels; reg-staged {load t+1; compute t; write t+1;
// barrier}. Panel image is pre-swizzled -> staging is a linear copy.
template<int NS, int FP32IN, int BF16OUT>
__global__ __launch_bounds__(256, 3) void gemm_pipe(
    const void* __restrict__ Ain, const unsigned short* __restrict__ Wsw,
    const float* __restrict__ bias, void* __restrict__ Cout, int Mrows) {
  __shared__ alignas(16) unsigned short Bsm[2][32 * 384];   // 49152 B
  const int tid = threadIdx.x;
  const int wave = tid >> 6, lane = tid & 63, g = lane >> 4, li = lane & 15;
  const int tb = blockIdx.x * 64 + wave * 16;
  const int arow = tb + li;
  const int soff = wave * 6 * 512 + lane * 8;   // this thread's staging offset

  // A-fragments, loaded once (fp32->bf16 convert for the qkv gemm)
  bf16x8 afr[12];
  if (arow < Mrows) {
    if (FP32IN) {
      const float* ap = (const float*)Ain + (size_t)arow * 384 + g * 8;
      #pragma unroll
      for (int ks = 0; ks < 12; ++ks) {
        float4 f0 = *(const float4*)(ap + ks * 32);
        float4 f1 = *(const float4*)(ap + ks * 32 + 4);
        BF8 t;
        t.u[0] = f2bf(f0.x); t.u[1] = f2bf(f0.y); t.u[2] = f2bf(f0.z); t.u[3] = f2bf(f0.w);
        t.u[4] = f2bf(f1.x); t.u[5] = f2bf(f1.y); t.u[6] = f2bf(f1.z); t.u[7] = f2bf(f1.w);
        afr[ks] = t.v;
      }
    } else {
      const unsigned short* ap = (const unsigned short*)Ain + (size_t)arow * 384 + g * 8;
      #pragma unroll
      for (int ks = 0; ks < 12; ++ks) afr[ks] = *(const bf16x8*)(ap + ks * 32);
    }
  } else {
    bf16x8 z = zbf8();
    #pragma unroll
    for (int ks = 0; ks < 12; ++ks) afr[ks] = z;
  }

  uint4 st[6];
  // prologue: stage slice 0
  {
    const unsigned short* p = Wsw + soff;
    #pragma unroll
    for (int i = 0; i < 6; ++i) st[i] = *(const uint4*)(p + i * 512);
    unsigned short* d = &Bsm[0][soff];
    #pragma unroll
    for (int i = 0; i < 6; ++i) *(uint4*)(d + i * 512) = st[i];
  }
  __syncthreads();

  #pragma unroll 1
  for (int ns = 0; ns < NS; ++ns) {
    const int cur = ns & 1;
    // issue next panel's loads early (latency hides under compute)
    if (ns + 1 < NS) {
      const unsigned short* p = Wsw + (size_t)(ns + 1) * 12288 + soff;
      #pragma unroll
      for (int i = 0; i < 6; ++i) st[i] = *(const uint4*)(p + i * 512);
    }

    // compute slice ns from Bsm[cur]
    f32x4 acc[2];
    acc[0] = (f32x4){0.f, 0.f, 0.f, 0.f};
    acc[1] = (f32x4){0.f, 0.f, 0.f, 0.f};
    #pragma unroll
    for (int k2 = 0; k2 < 12; ++k2) {
      #pragma unroll
      for (int nt = 0; nt < 2; ++nt) {
        bf16x8 bf = *(const bf16x8*)&Bsm[cur][(nt * 16 + li) * 384 +
                                             (((k2 * 4 + g) ^ (li & 7)) << 3)];
        acc[nt] = __builtin_amdgcn_mfma_f32_16x16x32_bf16(afr[k2], bf, acc[nt], 0, 0, 0);
      }
    }

    // C-write for this slice
    #pragma unroll
    for (int nt = 0; nt < 2; ++nt) {
      int col = ns * 32 + nt * 16 + li;
      float bv = bias[col];
      #pragma unroll
      for (int r4 = 0; r4 < 4; ++r4) {
        int row = tb + g * 4 + r4;
        if (row < Mrows) {
          float v = acc[nt][r4] + bv;
          if (BF16OUT) ((unsigned short*)Cout)[(size_t)row * (NS * 32) + col] = f2bf(v);
          else         ((float*)Cout)[(size_t)row * (NS * 32) + col] = v;
        }
      }
    }

    // write next panel late (buf cur^1 was last read at slice ns-1; the ns-1
    // barrier guarantees all waves are done with it)
    if (ns + 1 < NS) {
      unsigned short* d = &Bsm[cur ^ 1][soff];
      #pragma unroll
      for (int i = 0; i < 6; ++i) *(uint4*)(d + i * 512) = st[i];
    }
    __syncthreads();
  }
}

// ---------------- attn: per-window, q/K/V from qkv buffer (r7 verbatim) ----
#define AT_Q 0                   // [49][384] swizzled (scaled q)
#define AT_K (49*384)            // [49][128] swizzled K chunk
#define AT_V (AT_K + 49*128)     // [49][138] plain V chunk (bank-spread)
#define AT_ELEMS (AT_V + 49*138)

__global__ __launch_bounds__(512, 4) void attn_kernel(
    const unsigned short* __restrict__ qkv,   // [WB*49][1152]
    const float* __restrict__ cmb,
    unsigned short* __restrict__ Obuf,        // [WB*49][384]
    int wb0) {
  __shared__ unsigned short lds[AT_ELEMS];
  const int tid  = threadIdx.x;
  const int wave = tid >> 6, lane = tid & 63;
  const int g = lane >> 4, li = lane & 15;
  const int relw = blockIdx.x;
  const int wi = (wb0 + relw) & 63;
  const size_t rowbase = (size_t)relw * 49;
  const int mgrp = wave >> 1, ng = wave & 1;
  const int arow = mgrp * 16 + li;

  // stage q [49][384] (already scaled)
  #pragma unroll
  for (int it = 0; it < 5; ++it) {
    int gidx = it * 512 + tid;
    if (gidx < 2352) {
      int row = gidx / 48, gc = gidx % 48;
      bf16x8 v = *(const bf16x8*)(qkv + (rowbase + row) * 1152 + gc * 8);
      *(bf16x8*)&lds[AT_Q + row * 384 + ((gc ^ (row & 7)) << 3)] = v;
    }
  }

  #pragma unroll 1
  for (int c = 0; c < 3; ++c) {
    if (c) __syncthreads();
    // stage K chunk [49][128] swizzled
    #pragma unroll
    for (int it = 0; it < 2; ++it) {
      int gidx = it * 512 + tid;
      if (gidx < 784) {
        int row = gidx >> 4, gc = gidx & 15;
        bf16x8 v = *(const bf16x8*)(qkv + (rowbase + row) * 1152 + 384 + c * 128 + gc * 8);
        *(bf16x8*)&lds[AT_K + row * 128 + ((gc ^ (row & 7)) << 3)] = v;
      }
    }
    // stage V chunk [49][138] row-major
    #pragma unroll
    for (int it = 0; it < 2; ++it) {
      int gidx = it * 512 + tid;
      if (gidx < 784) {
        int row = gidx >> 4, gc = gidx & 15;
        BF8 v;
        v.q = *(const uint4*)(qkv + (rowbase + row) * 1152 + 768 + c * 128 + gc * 8);
        int e = AT_V + row * 138 + gc * 8;
        *(unsigned*)&lds[e]     = v.q.x;
        *(unsigned*)&lds[e + 2] = v.q.y;
        *(unsigned*)&lds[e + 4] = v.q.z;
        *(unsigned*)&lds[e + 6] = v.q.w;
      }
    }
    __syncthreads();

    #pragma unroll 1
    for (int b = 0; b < 2; ++b) {
      const int hh = ng * 2 + b;
      const int h  = c * 4 + hh;

      bf16x8 qa = (arow < NTOK)
          ? *(const bf16x8*)&lds[AT_Q + arow * 384 + (((h * 4 + g) ^ (arow & 7)) << 3)]
          : zbf8();

      f32x4 sv[4];
      #pragma unroll
      for (int nt = 0; nt < 4; ++nt) {
        int tok = nt * 16 + li;
        bf16x8 kf = (tok < NTOK)
            ? *(const bf16x8*)&lds[AT_K + tok * 128 + (((hh * 4 + g) ^ (tok & 7)) << 3)]
            : zbf8();
        f32x4 z4 = (f32x4){0.f, 0.f, 0.f, 0.f};
        sv[nt] = __builtin_amdgcn_mfma_f32_16x16x32_bf16(kf, qa, z4, 0, 0, 0);
      }

      const float* cb = cmb + (size_t)(wi * HEADS + h) * (NTOK * NTOK);
      #pragma unroll
      for (int nt = 0; nt < 4; ++nt) {
        #pragma unroll
        for (int r4 = 0; r4 < 4; ++r4) {
          int tok = nt * 16 + g * 4 + r4;
          float v;
          if (tok < NTOK) {
            v = sv[nt][r4];
            if (arow < NTOK) v += cb[tok * NTOK + arow];
          } else {
            v = -1e30f;
          }
          sv[nt][r4] = v;
        }
      }

      float m = -1e30f;
      #pragma unroll
      for (int nt = 0; nt < 4; ++nt)
        #pragma unroll
        for (int r4 = 0; r4 < 4; ++r4) m = fmaxf(m, sv[nt][r4]);
      m = fmaxf(m, __shfl_xor(m, 16));
      m = fmaxf(m, __shfl_xor(m, 32));
      float s = 0.f;
      #pragma unroll
      for (int nt = 0; nt < 4; ++nt)
        #pragma unroll
        for (int r4 = 0; r4 < 4; ++r4) {
          float e = __expf(sv[nt][r4] - m);
          sv[nt][r4] = e;
          s += e;
        }
      s += __shfl_xor(s, 16);
      s += __shfl_xor(s, 32);
      float inv = 1.f / s;
      #pragma unroll
      for (int nt = 0; nt < 4; ++nt)
        #pragma unroll
        for (int r4 = 0; r4 < 4; ++r4) sv[nt][r4] *= inv;

      bf16x8 pa[2];
      #pragma unroll
      for (int k2 = 0; k2 < 2; ++k2) {
        BF8 pf;
        #pragma unroll
        for (int j = 0; j < 8; ++j) {
          int srcLane = (((g * 2 + (j >> 2)) & 3) << 4) | li;
          float v0 = __shfl(sv[k2 * 2][j & 3], srcLane);
          float v1 = __shfl(sv[k2 * 2 + 1][j & 3], srcLane);
          pf.u[j] = f2bf((g >= 2) ? v1 : v0);
        }
        pa[k2] = pf.v;
      }

      f32x4 oa[2];
      oa[0] = (f32x4){0.f, 0.f, 0.f, 0.f};
      oa[1] = (f32x4){0.f, 0.f, 0.f, 0.f};
      #pragma unroll
      for (int k2 = 0; k2 < 2; ++k2) {
        #pragma unroll
        for (int nt2 = 0; nt2 < 2; ++nt2) {
          BF8 vb;
          int ch = hh * 32 + nt2 * 16 + li;
          #pragma unroll
          for (int j = 0; j < 8; ++j) {
            int tok = k2 * 32 + g * 8 + j;
            vb.u[j] = (tok < NTOK) ? lds[AT_V + tok * 138 + ch] : (unsigned short)0;
          }
          oa[nt2] = __builtin_amdgcn_mfma_f32_16x16x32_bf16(pa[k2], vb.v, oa[nt2], 0, 0, 0);
        }
      }

      #pragma unroll
      for (int nt2 = 0; nt2 < 2; ++nt2) {
        int col = h * 32 + nt2 * 16 + li;
        #pragma unroll
        for (int r4 = 0; r4 < 4; ++r4) {
          int row = mgrp * 16 + g * 4 + r4;
          if (row < NTOK)
            Obuf[(rowbase + row) * 384 + col] = f2bf(oa[nt2][r4]);
        }
      }
    }
  }
}

extern "C" void kernel_launch(void* const* d_in, const int* in_sizes, int n_in,
                              void* d_out, int out_size, void* d_ws, size_t ws_size,
                              hipStream_t stream) {
  (void)in_sizes; (void)n_in; (void)out_size;
  const float* x          = (const float*)d_in[0];
  const float* mask       = (const float*)d_in[1];
  const float* qkv_w      = (const float*)d_in[2];
  const float* qkv_b      = (const float*)d_in[3];
  const float* proj_w     = (const float*)d_in[4];
  const float* proj_b     = (const float*)d_in[5];
  const float* bias_table = (const float*)d_in[6];
  const int*   rel_idx    = (const int*)d_in[7];
  float* out = (float*)d_out;

  char* ws = (char*)d_ws;
  size_t off = 0;
  unsigned short* wq  = (unsigned short*)(ws + off); off += (size_t)QKV_ELEMS * 2;
  unsigned short* wp  = (unsigned short*)(ws + off); off += (size_t)PROJ_ELEMS * 2;
  float*          qb2 = (float*)(ws + off);          off += (size_t)QKV_OC * 4;
  float*          cmb = (float*)(ws + off);          off += (size_t)CMB_ELEMS * 4;
  const size_t fixed = off;

  // batch size: prefer WB=1024 (qkv slice 116 MB -> L3-resident)
  const int cands[7] = {1024, 2048, 512, 4096, 256, 128, 64};
  int WB = 64;
  for (int ci = 0; ci < 7; ++ci) {
    size_t need = fixed + (size_t)cands[ci] * 49 * (1152 + 384) * 2;
    if (need <= ws_size) { WB = cands[ci]; break; }
  }
  unsigned short* qkv = (unsigned short*)(ws + fixed);
  unsigned short* xb  = qkv + (size_t)WB * 49 * 1152;   // O buffer (bf16)

  const int prep_total = QKV_ELEMS + PROJ_ELEMS + CMB_ELEMS + QKV_OC;
  prep_kernel<<<(prep_total + 255) / 256, 256, 0, stream>>>(
      qkv_w, proj_w, bias_table, rel_idx, mask, qkv_b, wq, wp, cmb, qb2);

  const int NB = 4096 / WB;
  const int Mrows = WB * 49;
  const int grid = (Mrows + 63) / 64;
  for (int b = 0; b < NB; ++b) {
    gemm_pipe<36, 1, 1><<<grid, 256, 0, stream>>>(
        (const void*)(x + (size_t)b * Mrows * 384), wq, qb2, (void*)qkv, Mrows);
    attn_kernel<<<WB, 512, 0, stream>>>(qkv, cmb, xb, b * WB);
    gemm_pipe<12, 0, 0><<<grid, 256, 0, stream>>>(
        (const void*)xb, wp, proj_b, (void*)(out + (size_t)b * Mrows * 384), Mrows);
  }
}

// Round 10
// 1212.453 us; speedup vs baseline: 1.8172x; 1.8172x over previous
//
#include <hip/hip_runtime.h>

// Swin window attention, round 10: split pipeline; GEMM staging via async
// global_load_lds (m97 pattern). r9 post-mortem: reg-staged pipeline spilled
// st[6] to scratch (WRITE 753 MB = out 115 + ~640 MB panel-sized spills/slice).
// Fix: zero staging registers. Pre-swizzled weight image (already in prep)
// makes the panel a LINEAR copy -> global_load_lds applies (linear LDS dest,
// swizzle baked into global source). BN=32 double-buffered panels, per slice:
// {issue async loads for t+1 into buf^1; compute t; C-write; barrier(=vmcnt
// drain)}. Attn kernel unchanged (r7-verified).

#define NTOK 49
#define DIM 384
#define HEADS 12
#define QKV_OC 1152
#define QKV_ELEMS (1152*384)
#define PROJ_ELEMS (384*384)
#define CMB_ELEMS (64*12*49*49)
#define SCALE 0.17677669529663687f

typedef __attribute__((ext_vector_type(8))) __bf16 bf16x8;
typedef __attribute__((ext_vector_type(4))) float f32x4;

union BF8 { bf16x8 v; unsigned short u[8]; uint4 q; };

#define GLOAD_LDS16(gp, lp)                                                  \
  __builtin_amdgcn_global_load_lds(                                          \
      (const __attribute__((address_space(1))) void*)(gp),                   \
      (__attribute__((address_space(3))) void*)(lp), 16, 0, 0)

__device__ __forceinline__ unsigned short f2bf(float f) {
  union { float f; unsigned u; } x; x.f = f;
  unsigned r = x.u + 0x7fffu + ((x.u >> 16) & 1u);   // RNE
  return (unsigned short)(r >> 16);
}

__device__ __forceinline__ bf16x8 zbf8() {
  BF8 z;
  #pragma unroll
  for (int j = 0; j < 8; ++j) z.u[j] = 0;
  return z.v;
}

// ---- prep: weights -> bf16 pre-swizzled image (scale folded), cmb, bias ----
// image[c][s*8+e] = W[c][(s^(c&7))*8 + e]  (granule swizzle baked in)
__global__ void prep_kernel(const float* __restrict__ qkv_w,
                            const float* __restrict__ proj_w,
                            const float* __restrict__ bias_table,
                            const int* __restrict__ rel_idx,
                            const float* __restrict__ mask,
                            const float* __restrict__ qkv_b,
                            unsigned short* __restrict__ wq,
                            unsigned short* __restrict__ wp,
                            float* __restrict__ cmb,
                            float* __restrict__ qb2) {
  int i = blockIdx.x * 256 + threadIdx.x;
  if (i < QKV_ELEMS) {
    int c = i / 384, j = i % 384, s = j >> 3, e = j & 7;
    float v = qkv_w[c * 384 + ((s ^ (c & 7)) << 3) + e];
    if (c < 384) v *= SCALE;                  // q out-cols get the softmax scale
    wq[i] = f2bf(v);
  } else if (i < QKV_ELEMS + PROJ_ELEMS) {
    int k = i - QKV_ELEMS;
    int c = k / 384, j = k % 384, s = j >> 3, e = j & 7;
    wp[k] = f2bf(proj_w[c * 384 + ((s ^ (c & 7)) << 3) + e]);
  } else if (i < QKV_ELEMS + PROJ_ELEMS + CMB_ELEMS) {
    int j = i - QKV_ELEMS - PROJ_ELEMS;
    // layout: ((wi*12 + h)*49 + tok)*49 + qrow
    int row = j % 49;
    int tok = (j / 49) % 49;
    int h   = (j / 2401) % 12;
    int wi  = j / (2401 * 12);
    cmb[j] = bias_table[rel_idx[row * 49 + tok] * HEADS + h]
           + mask[(wi * 49 + row) * 49 + tok];
  } else if (i < QKV_ELEMS + PROJ_ELEMS + CMB_ELEMS + QKV_OC) {
    int c = i - QKV_ELEMS - PROJ_ELEMS - CMB_ELEMS;
    qb2[c] = qkv_b[c] * (c < 384 ? SCALE : 1.0f);
  }
}

// ---- gemm_lds: C[M][NS*32] = A[M][384] @ W[NS*32][384]^T + bias -----------
// Block = 64 rows (4 waves x 16), A-frags resident (read once). NS slices of
// 32 out-cols; double-buffered [32][384] panels staged by global_load_lds
// (async, no staging regs). One barrier/slice; its vmcnt(0) drain completes
// the next panel and fences buffer reuse.
template<int NS, int FP32IN, int BF16OUT>
__global__ __launch_bounds__(256, 3) void gemm_lds(
    const void* __restrict__ Ain, const unsigned short* __restrict__ Wsw,
    const float* __restrict__ bias, void* __restrict__ Cout, int Mrows) {
  __shared__ alignas(16) unsigned short Bsm[2][32 * 384];   // 49152 B
  const int tid = threadIdx.x;
  const int wave = tid >> 6, lane = tid & 63, g = lane >> 4, li = lane & 15;
  const int tb = blockIdx.x * 64 + wave * 16;
  const int arow = tb + li;

  // A-fragments, loaded once (fp32->bf16 convert for the qkv gemm)
  bf16x8 afr[12];
  if (arow < Mrows) {
    if (FP32IN) {
      const float* ap = (const float*)Ain + (size_t)arow * 384 + g * 8;
      #pragma unroll
      for (int ks = 0; ks < 12; ++ks) {
        float4 f0 = *(const float4*)(ap + ks * 32);
        float4 f1 = *(const float4*)(ap + ks * 32 + 4);
        BF8 t;
        t.u[0] = f2bf(f0.x); t.u[1] = f2bf(f0.y); t.u[2] = f2bf(f0.z); t.u[3] = f2bf(f0.w);
        t.u[4] = f2bf(f1.x); t.u[5] = f2bf(f1.y); t.u[6] = f2bf(f1.z); t.u[7] = f2bf(f1.w);
        afr[ks] = t.v;
      }
    } else {
      const unsigned short* ap = (const unsigned short*)Ain + (size_t)arow * 384 + g * 8;
      #pragma unroll
      for (int ks = 0; ks < 12; ++ks) afr[ks] = *(const bf16x8*)(ap + ks * 32);
    }
  } else {
    bf16x8 z = zbf8();
    #pragma unroll
    for (int ks = 0; ks < 12; ++ks) afr[ks] = z;
  }

  // prologue: async-stage slice 0 into buf 0 (wave w covers 3072 u16)
  {
    const unsigned short* gs = Wsw + wave * 3072 + lane * 8;
    unsigned short* ls = &Bsm[0][wave * 3072];
    #pragma unroll
    for (int i = 0; i < 6; ++i) GLOAD_LDS16(gs + i * 512, ls + i * 512);
  }
  __syncthreads();   // vmcnt(0) drain -> slice 0 resident

  #pragma unroll 1
  for (int ns = 0; ns < NS; ++ns) {
    const int cur = ns & 1;
    // issue async loads for the next panel (into the buffer whose reads
    // completed before the previous barrier)
    if (ns + 1 < NS) {
      const unsigned short* gs = Wsw + (size_t)(ns + 1) * 12288 + wave * 3072 + lane * 8;
      unsigned short* ls = &Bsm[cur ^ 1][wave * 3072];
      #pragma unroll
      for (int i = 0; i < 6; ++i) GLOAD_LDS16(gs + i * 512, ls + i * 512);
    }

    // compute slice ns from Bsm[cur]
    f32x4 acc[2];
    acc[0] = (f32x4){0.f, 0.f, 0.f, 0.f};
    acc[1] = (f32x4){0.f, 0.f, 0.f, 0.f};
    #pragma unroll
    for (int k2 = 0; k2 < 12; ++k2) {
      #pragma unroll
      for (int nt = 0; nt < 2; ++nt) {
        bf16x8 bf = *(const bf16x8*)&Bsm[cur][(nt * 16 + li) * 384 +
                                             (((k2 * 4 + g) ^ (li & 7)) << 3)];
        acc[nt] = __builtin_amdgcn_mfma_f32_16x16x32_bf16(afr[k2], bf, acc[nt], 0, 0, 0);
      }
    }

    // C-write for this slice
    #pragma unroll
    for (int nt = 0; nt < 2; ++nt) {
      int col = ns * 32 + nt * 16 + li;
      float bv = bias[col];
      #pragma unroll
      for (int r4 = 0; r4 < 4; ++r4) {
        int row = tb + g * 4 + r4;
        if (row < Mrows) {
          float v = acc[nt][r4] + bv;
          if (BF16OUT) ((unsigned short*)Cout)[(size_t)row * (NS * 32) + col] = f2bf(v);
          else         ((float*)Cout)[(size_t)row * (NS * 32) + col] = v;
        }
      }
    }

    __syncthreads();   // drains next-panel loads; fences buffer reuse
  }
}

// ---------------- attn: per-window, q/K/V from qkv buffer (r7 verbatim) ----
#define AT_Q 0                   // [49][384] swizzled (scaled q)
#define AT_K (49*384)            // [49][128] swizzled K chunk
#define AT_V (AT_K + 49*128)     // [49][138] plain V chunk (bank-spread)
#define AT_ELEMS (AT_V + 49*138)

__global__ __launch_bounds__(512, 4) void attn_kernel(
    const unsigned short* __restrict__ qkv,   // [WB*49][1152]
    const float* __restrict__ cmb,
    unsigned short* __restrict__ Obuf,        // [WB*49][384]
    int wb0) {
  __shared__ unsigned short lds[AT_ELEMS];
  const int tid  = threadIdx.x;
  const int wave = tid >> 6, lane = tid & 63;
  const int g = lane >> 4, li = lane & 15;
  const int relw = blockIdx.x;
  const int wi = (wb0 + relw) & 63;
  const size_t rowbase = (size_t)relw * 49;
  const int mgrp = wave >> 1, ng = wave & 1;
  const int arow = mgrp * 16 + li;

  // stage q [49][384] (already scaled)
  #pragma unroll
  for (int it = 0; it < 5; ++it) {
    int gidx = it * 512 + tid;
    if (gidx < 2352) {
      int row = gidx / 48, gc = gidx % 48;
      bf16x8 v = *(const bf16x8*)(qkv + (rowbase + row) * 1152 + gc * 8);
      *(bf16x8*)&lds[AT_Q + row * 384 + ((gc ^ (row & 7)) << 3)] = v;
    }
  }

  #pragma unroll 1
  for (int c = 0; c < 3; ++c) {
    if (c) __syncthreads();
    // stage K chunk [49][128] swizzled
    #pragma unroll
    for (int it = 0; it < 2; ++it) {
      int gidx = it * 512 + tid;
      if (gidx < 784) {
        int row = gidx >> 4, gc = gidx & 15;
        bf16x8 v = *(const bf16x8*)(qkv + (rowbase + row) * 1152 + 384 + c * 128 + gc * 8);
        *(bf16x8*)&lds[AT_K + row * 128 + ((gc ^ (row & 7)) << 3)] = v;
      }
    }
    // stage V chunk [49][138] row-major
    #pragma unroll
    for (int it = 0; it < 2; ++it) {
      int gidx = it * 512 + tid;
      if (gidx < 784) {
        int row = gidx >> 4, gc = gidx & 15;
        BF8 v;
        v.q = *(const uint4*)(qkv + (rowbase + row) * 1152 + 768 + c * 128 + gc * 8);
        int e = AT_V + row * 138 + gc * 8;
        *(unsigned*)&lds[e]     = v.q.x;
        *(unsigned*)&lds[e + 2] = v.q.y;
        *(unsigned*)&lds[e + 4] = v.q.z;
        *(unsigned*)&lds[e + 6] = v.q.w;
      }
    }
    __syncthreads();

    #pragma unroll 1
    for (int b = 0; b < 2; ++b) {
      const int hh = ng * 2 + b;
      const int h  = c * 4 + hh;

      bf16x8 qa = (arow < NTOK)
          ? *(const bf16x8*)&lds[AT_Q + arow * 384 + (((h * 4 + g) ^ (arow & 7)) << 3)]
          : zbf8();

      f32x4 sv[4];
      #pragma unroll
      for (int nt = 0; nt < 4; ++nt) {
        int tok = nt * 16 + li;
        bf16x8 kf = (tok < NTOK)
            ? *(const bf16x8*)&lds[AT_K + tok * 128 + (((hh * 4 + g) ^ (tok & 7)) << 3)]
            : zbf8();
        f32x4 z4 = (f32x4){0.f, 0.f, 0.f, 0.f};
        sv[nt] = __builtin_amdgcn_mfma_f32_16x16x32_bf16(kf, qa, z4, 0, 0, 0);
      }

      const float* cb = cmb + (size_t)(wi * HEADS + h) * (NTOK * NTOK);
      #pragma unroll
      for (int nt = 0; nt < 4; ++nt) {
        #pragma unroll
        for (int r4 = 0; r4 < 4; ++r4) {
          int tok = nt * 16 + g * 4 + r4;
          float v;
          if (tok < NTOK) {
            v = sv[nt][r4];
            if (arow < NTOK) v += cb[tok * NTOK + arow];
          } else {
            v = -1e30f;
          }
          sv[nt][r4] = v;
        }
      }

      float m = -1e30f;
      #pragma unroll
      for (int nt = 0; nt < 4; ++nt)
        #pragma unroll
        for (int r4 = 0; r4 < 4; ++r4) m = fmaxf(m, sv[nt][r4]);
      m = fmaxf(m, __shfl_xor(m, 16));
      m = fmaxf(m, __shfl_xor(m, 32));
      float s = 0.f;
      #pragma unroll
      for (int nt = 0; nt < 4; ++nt)
        #pragma unroll
        for (int r4 = 0; r4 < 4; ++r4) {
          float e = __expf(sv[nt][r4] - m);
          sv[nt][r4] = e;
          s += e;
        }
      s += __shfl_xor(s, 16);
      s += __shfl_xor(s, 32);
      float inv = 1.f / s;
      #pragma unroll
      for (int nt = 0; nt < 4; ++nt)
        #pragma unroll
        for (int r4 = 0; r4 < 4; ++r4) sv[nt][r4] *= inv;

      bf16x8 pa[2];
      #pragma unroll
      for (int k2 = 0; k2 < 2; ++k2) {
        BF8 pf;
        #pragma unroll
        for (int j = 0; j < 8; ++j) {
          int srcLane = (((g * 2 + (j >> 2)) & 3) << 4) | li;
          float v0 = __shfl(sv[k2 * 2][j & 3], srcLane);
          float v1 = __shfl(sv[k2 * 2 + 1][j & 3], srcLane);
          pf.u[j] = f2bf((g >= 2) ? v1 : v0);
        }
        pa[k2] = pf.v;
      }

      f32x4 oa[2];
      oa[0] = (f32x4){0.f, 0.f, 0.f, 0.f};
      oa[1] = (f32x4){0.f, 0.f, 0.f, 0.f};
      #pragma unroll
      for (int k2 = 0; k2 < 2; ++k2) {
        #pragma unroll
        for (int nt2 = 0; nt2 < 2; ++nt2) {
          BF8 vb;
          int ch = hh * 32 + nt2 * 16 + li;
          #pragma unroll
          for (int j = 0; j < 8; ++j) {
            int tok = k2 * 32 + g * 8 + j;
            vb.u[j] = (tok < NTOK) ? lds[AT_V + tok * 138 + ch] : (unsigned short)0;
          }
          oa[nt2] = __builtin_amdgcn_mfma_f32_16x16x32_bf16(pa[k2], vb.v, oa[nt2], 0, 0, 0);
        }
      }

      #pragma unroll
      for (int nt2 = 0; nt2 < 2; ++nt2) {
        int col = h * 32 + nt2 * 16 + li;
        #pragma unroll
        for (int r4 = 0; r4 < 4; ++r4) {
          int row = mgrp * 16 + g * 4 + r4;
          if (row < NTOK)
            Obuf[(rowbase + row) * 384 + col] = f2bf(oa[nt2][r4]);
        }
      }
    }
  }
}

extern "C" void kernel_launch(void* const* d_in, const int* in_sizes, int n_in,
                              void* d_out, int out_size, void* d_ws, size_t ws_size,
                              hipStream_t stream) {
  (void)in_sizes; (void)n_in; (void)out_size;
  const float* x          = (const float*)d_in[0];
  const float* mask       = (const float*)d_in[1];
  const float* qkv_w      = (const float*)d_in[2];
  const float* qkv_b      = (const float*)d_in[3];
  const float* proj_w     = (const float*)d_in[4];
  const float* proj_b     = (const float*)d_in[5];
  const float* bias_table = (const float*)d_in[6];
  const int*   rel_idx    = (const int*)d_in[7];
  float* out = (float*)d_out;

  char* ws = (char*)d_ws;
  size_t off = 0;
  unsigned short* wq  = (unsigned short*)(ws + off); off += (size_t)QKV_ELEMS * 2;
  unsigned short* wp  = (unsigned short*)(ws + off); off += (size_t)PROJ_ELEMS * 2;
  float*          qb2 = (float*)(ws + off);          off += (size_t)QKV_OC * 4;
  float*          cmb = (float*)(ws + off);          off += (size_t)CMB_ELEMS * 4;
  const size_t fixed = off;

  // batch size: prefer WB=1024 (qkv slice 116 MB -> L3-resident)
  const int cands[7] = {1024, 2048, 512, 4096, 256, 128, 64};
  int WB = 64;
  for (int ci = 0; ci < 7; ++ci) {
    size_t need = fixed + (size_t)cands[ci] * 49 * (1152 + 384) * 2;
    if (need <= ws_size) { WB = cands[ci]; break; }
  }
  unsigned short* qkv = (unsigned short*)(ws + fixed);
  unsigned short* xb  = qkv + (size_t)WB * 49 * 1152;   // O buffer (bf16)

  const int prep_total = QKV_ELEMS + PROJ_ELEMS + CMB_ELEMS + QKV_OC;
  prep_kernel<<<(prep_total + 255) / 256, 256, 0, stream>>>(
      qkv_w, proj_w, bias_table, rel_idx, mask, qkv_b, wq, wp, cmb, qb2);

  const int NB = 4096 / WB;
  const int Mrows = WB * 49;
  const int grid = (Mrows + 63) / 64;
  for (int b = 0; b < NB; ++b) {
    gemm_lds<36, 1, 1><<<grid, 256, 0, stream>>>(
        (const void*)(x + (size_t)b * Mrows * 384), wq, qb2, (void*)qkv, Mrows);
    attn_kernel<<<WB, 512, 0, stream>>>(qkv, cmb, xb, b * WB);
    gemm_lds<12, 0, 0><<<grid, 256, 0, stream>>>(
        (const void*)xb, wp, proj_b, (void*)(out + (size_t)b * Mrows * 384), Mrows);
  }
}

// Round 11
// 1009.009 us; speedup vs baseline: 2.1836x; 1.2016x over previous
//
#include <hip/hip_runtime.h>

// Swin window attention, round 11: split pipeline; GEMM goes high-occupancy.
// r8/r9/r10 all pinned at ~180us with 49KB LDS -> 3 blocks/CU: per-slice
// barrier+drain exposed with too little co-resident work. Fix: BN=32
// SINGLE-buffered panel (24.5KB) -> 6 blocks/CU, grid fully resident, ~24
// waves/CU; inter-block overlap (m114) hides stage/drain latency.
// Everything else identical to r10 (pre-swizzled weight image, gload_lds
// staging, A-resident registers, attn/prep kernels).

#define NTOK 49
#define DIM 384
#define HEADS 12
#define QKV_OC 1152
#define QKV_ELEMS (1152*384)
#define PROJ_ELEMS (384*384)
#define CMB_ELEMS (64*12*49*49)
#define SCALE 0.17677669529663687f

typedef __attribute__((ext_vector_type(8))) __bf16 bf16x8;
typedef __attribute__((ext_vector_type(4))) float f32x4;

union BF8 { bf16x8 v; unsigned short u[8]; uint4 q; };

#define GLOAD_LDS16(gp, lp)                                                  \
  __builtin_amdgcn_global_load_lds(                                          \
      (const __attribute__((address_space(1))) void*)(gp),                   \
      (__attribute__((address_space(3))) void*)(lp), 16, 0, 0)

__device__ __forceinline__ unsigned short f2bf(float f) {
  union { float f; unsigned u; } x; x.f = f;
  unsigned r = x.u + 0x7fffu + ((x.u >> 16) & 1u);   // RNE
  return (unsigned short)(r >> 16);
}

__device__ __forceinline__ bf16x8 zbf8() {
  BF8 z;
  #pragma unroll
  for (int j = 0; j < 8; ++j) z.u[j] = 0;
  return z.v;
}

// ---- prep: weights -> bf16 pre-swizzled image (scale folded), cmb, bias ----
// image[c][s*8+e] = W[c][(s^(c&7))*8 + e]  (granule swizzle baked in)
__global__ void prep_kernel(const float* __restrict__ qkv_w,
                            const float* __restrict__ proj_w,
                            const float* __restrict__ bias_table,
                            const int* __restrict__ rel_idx,
                            const float* __restrict__ mask,
                            const float* __restrict__ qkv_b,
                            unsigned short* __restrict__ wq,
                            unsigned short* __restrict__ wp,
                            float* __restrict__ cmb,
                            float* __restrict__ qb2) {
  int i = blockIdx.x * 256 + threadIdx.x;
  if (i < QKV_ELEMS) {
    int c = i / 384, j = i % 384, s = j >> 3, e = j & 7;
    float v = qkv_w[c * 384 + ((s ^ (c & 7)) << 3) + e];
    if (c < 384) v *= SCALE;                  // q out-cols get the softmax scale
    wq[i] = f2bf(v);
  } else if (i < QKV_ELEMS + PROJ_ELEMS) {
    int k = i - QKV_ELEMS;
    int c = k / 384, j = k % 384, s = j >> 3, e = j & 7;
    wp[k] = f2bf(proj_w[c * 384 + ((s ^ (c & 7)) << 3) + e]);
  } else if (i < QKV_ELEMS + PROJ_ELEMS + CMB_ELEMS) {
    int j = i - QKV_ELEMS - PROJ_ELEMS;
    // layout: ((wi*12 + h)*49 + tok)*49 + qrow
    int row = j % 49;
    int tok = (j / 49) % 49;
    int h   = (j / 2401) % 12;
    int wi  = j / (2401 * 12);
    cmb[j] = bias_table[rel_idx[row * 49 + tok] * HEADS + h]
           + mask[(wi * 49 + row) * 49 + tok];
  } else if (i < QKV_ELEMS + PROJ_ELEMS + CMB_ELEMS + QKV_OC) {
    int c = i - QKV_ELEMS - PROJ_ELEMS - CMB_ELEMS;
    qb2[c] = qkv_b[c] * (c < 384 ? SCALE : 1.0f);
  }
}

// ---- gemm_lds: C[M][NS*32] = A[M][384] @ W[NS*32][384]^T + bias -----------
// Block = 64 rows (4 waves x 16), A-frags resident (read once). NS slices of
// 32 out-cols; SINGLE [32][384] panel (24.5KB LDS -> 6 blocks/CU) staged by
// global_load_lds. 2 barriers/slice; inter-block TLP hides the drain.
template<int NS, int FP32IN, int BF16OUT>
__global__ __launch_bounds__(256, 6) void gemm_lds(
    const void* __restrict__ Ain, const unsigned short* __restrict__ Wsw,
    const float* __restrict__ bias, void* __restrict__ Cout, int Mrows) {
  __shared__ alignas(16) unsigned short Bsm[32 * 384];   // 24576 B
  const int tid = threadIdx.x;
  const int wave = tid >> 6, lane = tid & 63, g = lane >> 4, li = lane & 15;
  const int tb = blockIdx.x * 64 + wave * 16;
  const int arow = tb + li;

  // A-fragments, loaded once (fp32->bf16 convert for the qkv gemm)
  bf16x8 afr[12];
  if (arow < Mrows) {
    if (FP32IN) {
      const float* ap = (const float*)Ain + (size_t)arow * 384 + g * 8;
      #pragma unroll
      for (int ks = 0; ks < 12; ++ks) {
        float4 f0 = *(const float4*)(ap + ks * 32);
        float4 f1 = *(const float4*)(ap + ks * 32 + 4);
        BF8 t;
        t.u[0] = f2bf(f0.x); t.u[1] = f2bf(f0.y); t.u[2] = f2bf(f0.z); t.u[3] = f2bf(f0.w);
        t.u[4] = f2bf(f1.x); t.u[5] = f2bf(f1.y); t.u[6] = f2bf(f1.z); t.u[7] = f2bf(f1.w);
        afr[ks] = t.v;
      }
    } else {
      const unsigned short* ap = (const unsigned short*)Ain + (size_t)arow * 384 + g * 8;
      #pragma unroll
      for (int ks = 0; ks < 12; ++ks) afr[ks] = *(const bf16x8*)(ap + ks * 32);
    }
  } else {
    bf16x8 z = zbf8();
    #pragma unroll
    for (int ks = 0; ks < 12; ++ks) afr[ks] = z;
  }

  #pragma unroll 1
  for (int ns = 0; ns < NS; ++ns) {
    // stage panel ns (linear copy; image pre-swizzled). 24KB: each wave 6KB.
    {
      const unsigned short* gs = Wsw + (size_t)ns * 12288 + wave * 3072 + lane * 8;
      unsigned short* ls = &Bsm[wave * 3072];
      #pragma unroll
      for (int i = 0; i < 6; ++i) GLOAD_LDS16(gs + i * 512, ls + i * 512);
    }
    __syncthreads();   // vmcnt(0) drain -> panel resident

    f32x4 acc[2];
    acc[0] = (f32x4){0.f, 0.f, 0.f, 0.f};
    acc[1] = (f32x4){0.f, 0.f, 0.f, 0.f};
    #pragma unroll
    for (int k2 = 0; k2 < 12; ++k2) {
      #pragma unroll
      for (int nt = 0; nt < 2; ++nt) {
        bf16x8 bf = *(const bf16x8*)&Bsm[(nt * 16 + li) * 384 +
                                         (((k2 * 4 + g) ^ (li & 7)) << 3)];
        acc[nt] = __builtin_amdgcn_mfma_f32_16x16x32_bf16(afr[k2], bf, acc[nt], 0, 0, 0);
      }
    }

    // C-write for this slice
    #pragma unroll
    for (int nt = 0; nt < 2; ++nt) {
      int col = ns * 32 + nt * 16 + li;
      float bv = bias[col];
      #pragma unroll
      for (int r4 = 0; r4 < 4; ++r4) {
        int row = tb + g * 4 + r4;
        if (row < Mrows) {
          float v = acc[nt][r4] + bv;
          if (BF16OUT) ((unsigned short*)Cout)[(size_t)row * (NS * 32) + col] = f2bf(v);
          else         ((float*)Cout)[(size_t)row * (NS * 32) + col] = v;
        }
      }
    }
    __syncthreads();   // all waves done reading panel before next overwrite
  }
}

// ---------------- attn: per-window, q/K/V from qkv buffer (r7 verbatim) ----
#define AT_Q 0                   // [49][384] swizzled (scaled q)
#define AT_K (49*384)            // [49][128] swizzled K chunk
#define AT_V (AT_K + 49*128)     // [49][138] plain V chunk (bank-spread)
#define AT_ELEMS (AT_V + 49*138)

__global__ __launch_bounds__(512, 4) void attn_kernel(
    const unsigned short* __restrict__ qkv,   // [WB*49][1152]
    const float* __restrict__ cmb,
    unsigned short* __restrict__ Obuf,        // [WB*49][384]
    int wb0) {
  __shared__ unsigned short lds[AT_ELEMS];
  const int tid  = threadIdx.x;
  const int wave = tid >> 6, lane = tid & 63;
  const int g = lane >> 4, li = lane & 15;
  const int relw = blockIdx.x;
  const int wi = (wb0 + relw) & 63;
  const size_t rowbase = (size_t)relw * 49;
  const int mgrp = wave >> 1, ng = wave & 1;
  const int arow = mgrp * 16 + li;

  // stage q [49][384] (already scaled)
  #pragma unroll
  for (int it = 0; it < 5; ++it) {
    int gidx = it * 512 + tid;
    if (gidx < 2352) {
      int row = gidx / 48, gc = gidx % 48;
      bf16x8 v = *(const bf16x8*)(qkv + (rowbase + row) * 1152 + gc * 8);
      *(bf16x8*)&lds[AT_Q + row * 384 + ((gc ^ (row & 7)) << 3)] = v;
    }
  }

  #pragma unroll 1
  for (int c = 0; c < 3; ++c) {
    if (c) __syncthreads();
    // stage K chunk [49][128] swizzled
    #pragma unroll
    for (int it = 0; it < 2; ++it) {
      int gidx = it * 512 + tid;
      if (gidx < 784) {
        int row = gidx >> 4, gc = gidx & 15;
        bf16x8 v = *(const bf16x8*)(qkv + (rowbase + row) * 1152 + 384 + c * 128 + gc * 8);
        *(bf16x8*)&lds[AT_K + row * 128 + ((gc ^ (row & 7)) << 3)] = v;
      }
    }
    // stage V chunk [49][138] row-major
    #pragma unroll
    for (int it = 0; it < 2; ++it) {
      int gidx = it * 512 + tid;
      if (gidx < 784) {
        int row = gidx >> 4, gc = gidx & 15;
        BF8 v;
        v.q = *(const uint4*)(qkv + (rowbase + row) * 1152 + 768 + c * 128 + gc * 8);
        int e = AT_V + row * 138 + gc * 8;
        *(unsigned*)&lds[e]     = v.q.x;
        *(unsigned*)&lds[e + 2] = v.q.y;
        *(unsigned*)&lds[e + 4] = v.q.z;
        *(unsigned*)&lds[e + 6] = v.q.w;
      }
    }
    __syncthreads();

    #pragma unroll 1
    for (int b = 0; b < 2; ++b) {
      const int hh = ng * 2 + b;
      const int h  = c * 4 + hh;

      bf16x8 qa = (arow < NTOK)
          ? *(const bf16x8*)&lds[AT_Q + arow * 384 + (((h * 4 + g) ^ (arow & 7)) << 3)]
          : zbf8();

      f32x4 sv[4];
      #pragma unroll
      for (int nt = 0; nt < 4; ++nt) {
        int tok = nt * 16 + li;
        bf16x8 kf = (tok < NTOK)
            ? *(const bf16x8*)&lds[AT_K + tok * 128 + (((hh * 4 + g) ^ (tok & 7)) << 3)]
            : zbf8();
        f32x4 z4 = (f32x4){0.f, 0.f, 0.f, 0.f};
        sv[nt] = __builtin_amdgcn_mfma_f32_16x16x32_bf16(kf, qa, z4, 0, 0, 0);
      }

      const float* cb = cmb + (size_t)(wi * HEADS + h) * (NTOK * NTOK);
      #pragma unroll
      for (int nt = 0; nt < 4; ++nt) {
        #pragma unroll
        for (int r4 = 0; r4 < 4; ++r4) {
          int tok = nt * 16 + g * 4 + r4;
          float v;
          if (tok < NTOK) {
            v = sv[nt][r4];
            if (arow < NTOK) v += cb[tok * NTOK + arow];
          } else {
            v = -1e30f;
          }
          sv[nt][r4] = v;
        }
      }

      float m = -1e30f;
      #pragma unroll
      for (int nt = 0; nt < 4; ++nt)
        #pragma unroll
        for (int r4 = 0; r4 < 4; ++r4) m = fmaxf(m, sv[nt][r4]);
      m = fmaxf(m, __shfl_xor(m, 16));
      m = fmaxf(m, __shfl_xor(m, 32));
      float s = 0.f;
      #pragma unroll
      for (int nt = 0; nt < 4; ++nt)
        #pragma unroll
        for (int r4 = 0; r4 < 4; ++r4) {
          float e = __expf(sv[nt][r4] - m);
          sv[nt][r4] = e;
          s += e;
        }
      s += __shfl_xor(s, 16);
      s += __shfl_xor(s, 32);
      float inv = 1.f / s;
      #pragma unroll
      for (int nt = 0; nt < 4; ++nt)
        #pragma unroll
        for (int r4 = 0; r4 < 4; ++r4) sv[nt][r4] *= inv;

      bf16x8 pa[2];
      #pragma unroll
      for (int k2 = 0; k2 < 2; ++k2) {
        BF8 pf;
        #pragma unroll
        for (int j = 0; j < 8; ++j) {
          int srcLane = (((g * 2 + (j >> 2)) & 3) << 4) | li;
          float v0 = __shfl(sv[k2 * 2][j & 3], srcLane);
          float v1 = __shfl(sv[k2 * 2 + 1][j & 3], srcLane);
          pf.u[j] = f2bf((g >= 2) ? v1 : v0);
        }
        pa[k2] = pf.v;
      }

      f32x4 oa[2];
      oa[0] = (f32x4){0.f, 0.f, 0.f, 0.f};
      oa[1] = (f32x4){0.f, 0.f, 0.f, 0.f};
      #pragma unroll
      for (int k2 = 0; k2 < 2; ++k2) {
        #pragma unroll
        for (int nt2 = 0; nt2 < 2; ++nt2) {
          BF8 vb;
          int ch = hh * 32 + nt2 * 16 + li;
          #pragma unroll
          for (int j = 0; j < 8; ++j) {
            int tok = k2 * 32 + g * 8 + j;
            vb.u[j] = (tok < NTOK) ? lds[AT_V + tok * 138 + ch] : (unsigned short)0;
          }
          oa[nt2] = __builtin_amdgcn_mfma_f32_16x16x32_bf16(pa[k2], vb.v, oa[nt2], 0, 0, 0);
        }
      }

      #pragma unroll
      for (int nt2 = 0; nt2 < 2; ++nt2) {
        int col = h * 32 + nt2 * 16 + li;
        #pragma unroll
        for (int r4 = 0; r4 < 4; ++r4) {
          int row = mgrp * 16 + g * 4 + r4;
          if (row < NTOK)
            Obuf[(rowbase + row) * 384 + col] = f2bf(oa[nt2][r4]);
        }
      }
    }
  }
}

extern "C" void kernel_launch(void* const* d_in, const int* in_sizes, int n_in,
                              void* d_out, int out_size, void* d_ws, size_t ws_size,
                              hipStream_t stream) {
  (void)in_sizes; (void)n_in; (void)out_size;
  const float* x          = (const float*)d_in[0];
  const float* mask       = (const float*)d_in[1];
  const float* qkv_w      = (const float*)d_in[2];
  const float* qkv_b      = (const float*)d_in[3];
  const float* proj_w     = (const float*)d_in[4];
  const float* proj_b     = (const float*)d_in[5];
  const float* bias_table = (const float*)d_in[6];
  const int*   rel_idx    = (const int*)d_in[7];
  float* out = (float*)d_out;

  char* ws = (char*)d_ws;
  size_t off = 0;
  unsigned short* wq  = (unsigned short*)(ws + off); off += (size_t)QKV_ELEMS * 2;
  unsigned short* wp  = (unsigned short*)(ws + off); off += (size_t)PROJ_ELEMS * 2;
  float*          qb2 = (float*)(ws + off);          off += (size_t)QKV_OC * 4;
  float*          cmb = (float*)(ws + off);          off += (size_t)CMB_ELEMS * 4;
  const size_t fixed = off;

  // batch size: prefer WB=1024 (qkv slice 116 MB -> L3-resident)
  const int cands[7] = {1024, 2048, 512, 4096, 256, 128, 64};
  int WB = 64;
  for (int ci = 0; ci < 7; ++ci) {
    size_t need = fixed + (size_t)cands[ci] * 49 * (1152 + 384) * 2;
    if (need <= ws_size) { WB = cands[ci]; break; }
  }
  unsigned short* qkv = (unsigned short*)(ws + fixed);
  unsigned short* xb  = qkv + (size_t)WB * 49 * 1152;   // O buffer (bf16)

  const int prep_total = QKV_ELEMS + PROJ_ELEMS + CMB_ELEMS + QKV_OC;
  prep_kernel<<<(prep_total + 255) / 256, 256, 0, stream>>>(
      qkv_w, proj_w, bias_table, rel_idx, mask, qkv_b, wq, wp, cmb, qb2);

  const int NB = 4096 / WB;
  const int Mrows = WB * 49;
  const int grid = (Mrows + 63) / 64;
  for (int b = 0; b < NB; ++b) {
    gemm_lds<36, 1, 1><<<grid, 256, 0, stream>>>(
        (const void*)(x + (size_t)b * Mrows * 384), wq, qb2, (void*)qkv, Mrows);
    attn_kernel<<<WB, 512, 0, stream>>>(qkv, cmb, xb, b * WB);
    gemm_lds<12, 0, 0><<<grid, 256, 0, stream>>>(
        (const void*)xb, wp, proj_b, (void*)(out + (size_t)b * Mrows * 384), Mrows);
  }
}